// Round 1
// baseline (78.031 us; speedup 1.0000x reference)
//
#include <hip/hip_runtime.h>

// QuantumLLPModel: probs[b,s] for s in [0,10) over 16 qubits.
// Key identity: states 0..9 only differ in qubits 12..15; the shared
// product over qubits 0..11 cancels under normalization, as do the 1/2
// factors of cos^2(a/2)=(1+cos a)/2. So per sample: 4 cos, ~20 FMAs.
static constexpr float KPI = 3.14159265358979323846f;

__global__ __launch_bounds__(256) void qllp_kernel(
    const float* __restrict__ x, const float* __restrict__ params,
    float* __restrict__ out, int batch)
{
    __shared__ float sm[2560];  // 256 samples x 10 classes, flat sample-major
    const int tid = threadIdx.x;
    const long long b = (long long)blockIdx.x * 256 + tid;

    // uniform (scalarized) param loads, qubits 12..15 only
    const float q12 = params[12];
    const float q13 = params[13];
    const float q14 = params[14];
    const float q15 = params[15];

    if (b < batch) {
        // row tail: elements 12..15 of the 16-float row, 16B-aligned
        const float4 xv = reinterpret_cast<const float4*>(x)[b * 4 + 3];
        const float c12 = __cosf(fmaf(KPI, xv.x, q12));
        const float c13 = __cosf(fmaf(KPI, xv.y, q13));
        const float c14 = __cosf(fmaf(KPI, xv.z, q14));
        const float c15 = __cosf(fmaf(KPI, xv.w, q15));
        // unnormalized per-qubit probs (factor 1/2 cancels in normalization)
        const float a0 = 1.f + c12, a1 = 1.f - c12;   // qubit 12 (bit 3)
        const float b0 = 1.f + c13, b1 = 1.f - c13;   // qubit 13 (bit 2)
        const float d0 = 1.f + c14, d1 = 1.f - c14;   // qubit 14 (bit 1)
        const float e0 = 1.f + c15, e1 = 1.f - c15;   // qubit 15 (bit 0)
        // lower-pair products m[s&3], upper-pair products n[s>>2]
        const float m0 = d0 * e0, m1 = d0 * e1, m2 = d1 * e0, m3 = d1 * e1;
        const float n0 = a0 * b0, n1 = a0 * b1, n2 = a1 * b0;
        float t[10];
        t[0] = n0 * m0; t[1] = n0 * m1; t[2] = n0 * m2; t[3] = n0 * m3;
        t[4] = n1 * m0; t[5] = n1 * m1; t[6] = n1 * m2; t[7] = n1 * m3;
        t[8] = n2 * m0; t[9] = n2 * m1;
        const float sum = ((t[0] + t[1]) + (t[2] + t[3]))
                        + ((t[4] + t[5]) + (t[6] + t[7]))
                        + (t[8] + t[9]);
        const float inv = 1.0f / sum;
#pragma unroll
        for (int j = 0; j < 10; ++j) sm[tid * 10 + j] = t[j] * inv;
    }
    __syncthreads();
    // coalesced stride-1 dword writes of the block's 2560 contiguous floats
    float* outb = out + (long long)blockIdx.x * 2560;
    const long long lim = (long long)batch * 10 - (long long)blockIdx.x * 2560;
#pragma unroll
    for (int k = 0; k < 10; ++k) {
        const int f = k * 256 + tid;
        if (f < lim) outb[f] = sm[f];
    }
}

extern "C" void kernel_launch(void* const* d_in, const int* in_sizes, int n_in,
                              void* d_out, int out_size, void* d_ws, size_t ws_size,
                              hipStream_t stream) {
    const float* x      = (const float*)d_in[0];
    const float* params = (const float*)d_in[1];
    float* out = (float*)d_out;
    const int batch  = in_sizes[0] / 16;
    const int blocks = (batch + 255) / 256;
    qllp_kernel<<<blocks, 256, 0, stream>>>(x, params, out, batch);
}